// Round 3
// baseline (1767.546 us; speedup 1.0000x reference)
//
#include <hip/hip_runtime.h>
#include <hip/hip_bf16.h>

#define B_ 2
#define T_ 2048
#define C_ 1024
#define H_ 16
#define D_ 64

typedef unsigned short u16;
typedef __bf16 bf16x8 __attribute__((ext_vector_type(8)));
typedef float floatx4 __attribute__((ext_vector_type(4)));

__device__ __forceinline__ float bf2f(u16 u) {
  union { unsigned int i; float f; } x; x.i = ((unsigned int)u) << 16; return x.f;
}
__device__ __forceinline__ u16 f2bf(float f) {
  union { float f; unsigned int i; } x; x.f = f;
  unsigned int r = x.i + 0x7fffu + ((x.i >> 16) & 1u);  // RNE
  return (u16)(r >> 16);
}

// ---------------------------------------------------------------------------
// fp32 -> bf16 convert (inputs arrive fp32; compute pipeline is bf16 MFMA)
// ---------------------------------------------------------------------------
__global__ __launch_bounds__(256) void cvt_f32_bf16(
    const float* __restrict__ src, u16* __restrict__ dst, int n4)
{
  const int i = (blockIdx.x * 256 + threadIdx.x);
  if (i < n4) {
    float4 f = ((const float4*)src)[i];
    ushort4 o;
    o.x = f2bf(f.x); o.y = f2bf(f.y); o.z = f2bf(f.z); o.w = f2bf(f.w);
    ((ushort4*)dst)[i] = o;
  }
}

// ---------------------------------------------------------------------------
// GEMM: Y[M,N] = X[M,K] @ W[N,K]^T + bias[N]   (torch Linear, K-contiguous
// on both operands -> "gemm_bt" pattern). bf16 in, fp32 accum.
// mode=1: bf16 out, remapped to [B,H,T,D] (m = b*T+t, n = h*D+d)  -> Yb
// mode=0: fp32 out, [M,N] row-major                               -> Yf
// ---------------------------------------------------------------------------
#define BM 64
#define BN 64
#define BK 32
#define LDK (BK + 8)  // padded u16 stride (80B, multiple of 16B -> b128 ok)

__global__ __launch_bounds__(256) void gemm_bt(
    const u16* __restrict__ X, const u16* __restrict__ W,
    const float* __restrict__ bias, u16* __restrict__ Yb,
    float* __restrict__ Yf, int M, int N, int K, int mode)
{
  __shared__ __align__(16) u16 As[BM][LDK];
  __shared__ __align__(16) u16 Bs[BN][LDK];

  const int tid  = threadIdx.x;
  const int wave = tid >> 6;
  const int lane = tid & 63;
  const int m0 = blockIdx.x * BM;
  const int n0 = blockIdx.y * BN;

  const int lrow = tid >> 2;        // 0..63
  const int lcol = (tid & 3) * 8;   // 0,8,16,24

  floatx4 acc[4] = {};

  for (int k0 = 0; k0 < K; k0 += BK) {
    *(uint4*)&As[lrow][lcol] =
        *(const uint4*)&X[(size_t)(m0 + lrow) * K + k0 + lcol];
    *(uint4*)&Bs[lrow][lcol] =
        *(const uint4*)&W[(size_t)(n0 + lrow) * K + k0 + lcol];
    __syncthreads();

    const int mrow = wave * 16 + (lane & 15);
    const int kof  = (lane >> 4) * 8;
    bf16x8 a = *(const bf16x8*)&As[mrow][kof];
#pragma unroll
    for (int j = 0; j < 4; ++j) {
      bf16x8 b = *(const bf16x8*)&Bs[j * 16 + (lane & 15)][kof];
      acc[j] = __builtin_amdgcn_mfma_f32_16x16x32_bf16(a, b, acc[j], 0, 0, 0);
    }
    __syncthreads();
  }

  // Epilogue. C/D layout: col = lane&15, row = (lane>>4)*4 + reg  [m89-verified]
  const int rbase = wave * 16 + (lane >> 4) * 4;
#pragma unroll
  for (int j = 0; j < 4; ++j) {
    const int n = n0 + j * 16 + (lane & 15);
    const float bv = bias[n];
#pragma unroll
    for (int r = 0; r < 4; ++r) {
      const int m = m0 + rbase + r;
      const float v = acc[j][r] + bv;
      if (mode) {
        const int b = m >> 11, t = m & (T_ - 1);
        const int h = n >> 6, d = n & (D_ - 1);
        Yb[(((size_t)b * H_ + h) * T_ + t) * D_ + d] = f2bf(v);
      } else {
        Yf[(size_t)m * N + n] = v;   // final output: fp32
      }
    }
  }
}

// ---------------------------------------------------------------------------
// Causal attention: one wave per query row. Q,K,V in [B*H, T, D] bf16.
// Output ctx in [B, T, C] bf16 (layout ready for the out-proj GEMM).
// ---------------------------------------------------------------------------
__global__ __launch_bounds__(256) void attn(
    const u16* __restrict__ Q, const u16* __restrict__ Kt,
    const u16* __restrict__ V, u16* __restrict__ O)
{
  __shared__ float sc[4][T_];   // 32 KB: per-wave score row
  __shared__ float qs[4][D_];   // 1 KB : per-wave query

  const int wave = threadIdx.x >> 6;
  const int lane = threadIdx.x & 63;
  const int row  = blockIdx.x * 4 + wave;   // global query row over B*H*T
  const int t  = row & (T_ - 1);
  const int bh = row >> 11;                  // T_ = 2048

  const u16* qptr = Q + ((size_t)bh * T_ + t) * D_;
  qs[wave][lane] = 0.125f * bf2f(qptr[lane]);   // pre-scale by 1/sqrt(D)
  __syncthreads();

  // Phase 1: scores s[k] = (q/8) . K[k], k = lane, lane+64, ... <= t
  float mmax = -1e30f;
  for (int k = lane; k <= t; k += 64) {
    const uint4* kp4 = (const uint4*)(Kt + ((size_t)bh * T_ + k) * D_);
    float s0 = 0.f, s1 = 0.f;
#pragma unroll
    for (int i = 0; i < 8; ++i) {
      uint4 u = kp4[i];
      const float* q8 = &qs[wave][i * 8];
      unsigned int w0 = u.x, w1 = u.y, w2 = u.z, w3 = u.w;
      s0 += q8[0] * __uint_as_float(w0 << 16);
      s1 += q8[1] * __uint_as_float(w0 & 0xffff0000u);
      s0 += q8[2] * __uint_as_float(w1 << 16);
      s1 += q8[3] * __uint_as_float(w1 & 0xffff0000u);
      s0 += q8[4] * __uint_as_float(w2 << 16);
      s1 += q8[5] * __uint_as_float(w2 & 0xffff0000u);
      s0 += q8[6] * __uint_as_float(w3 << 16);
      s1 += q8[7] * __uint_as_float(w3 & 0xffff0000u);
    }
    const float s = s0 + s1;
    sc[wave][k] = s;
    mmax = fmaxf(mmax, s);
  }
#pragma unroll
  for (int off = 32; off; off >>= 1)
    mmax = fmaxf(mmax, __shfl_xor(mmax, off));

  // Phase 2: exp + sum
  float sum = 0.f;
  for (int k = lane; k <= t; k += 64) {
    const float p = __expf(sc[wave][k] - mmax);
    sc[wave][k] = p;
    sum += p;
  }
#pragma unroll
  for (int off = 32; off; off >>= 1) sum += __shfl_xor(sum, off);
  const float inv = 1.f / sum;

  // Phase 3: o[d=lane] = sum_k p[k] * V[k][d]; V loads coalesced across lanes
  const u16* vcol = V + (size_t)bh * T_ * D_ + lane;
  float a0 = 0.f, a1 = 0.f, a2 = 0.f, a3 = 0.f;
  const int tend = t + 1;
  int k = 0;
  for (; k + 4 <= tend; k += 4) {
    a0 += sc[wave][k + 0] * bf2f(vcol[(size_t)(k + 0) * D_]);
    a1 += sc[wave][k + 1] * bf2f(vcol[(size_t)(k + 1) * D_]);
    a2 += sc[wave][k + 2] * bf2f(vcol[(size_t)(k + 2) * D_]);
    a3 += sc[wave][k + 3] * bf2f(vcol[(size_t)(k + 3) * D_]);
  }
  for (; k < tend; ++k) a0 += sc[wave][k] * bf2f(vcol[(size_t)k * D_]);
  const float o = ((a0 + a1) + (a2 + a3)) * inv;

  const int b = bh >> 4, h = bh & (H_ - 1);
  O[((size_t)b * T_ + t) * C_ + h * D_ + lane] = f2bf(o);
}

// ---------------------------------------------------------------------------
extern "C" void kernel_launch(void* const* d_in, const int* in_sizes, int n_in,
                              void* d_out, int out_size, void* d_ws, size_t ws_size,
                              hipStream_t stream) {
  const float* x  = (const float*)d_in[0];
  const float* Wq = (const float*)d_in[1];
  const float* bq = (const float*)d_in[2];
  const float* Wk = (const float*)d_in[3];
  const float* bk = (const float*)d_in[4];
  const float* Wv = (const float*)d_in[5];
  const float* bv = (const float*)d_in[6];
  const float* Wo = (const float*)d_in[7];
  const float* bo = (const float*)d_in[8];
  float* out = (float*)d_out;   // reference output dtype is float32

  const size_t NX = (size_t)B_ * T_ * C_;  // 4M elements
  const size_t NW = (size_t)C_ * C_;       // 1M elements

  u16* xb  = (u16*)d_ws;       // 8 MB
  u16* wqb = xb  + NX;         // 2 MB each
  u16* wkb = wqb + NW;
  u16* wvb = wkb + NW;
  u16* wob = wvb + NW;
  u16* q   = wob + NW;         // 8 MB each
  u16* k   = q   + NX;
  u16* v   = k   + NX;
  u16* ctx = v   + NX;         // total 48 MB

  cvt_f32_bf16<<<dim3(NX / 4 / 256), 256, 0, stream>>>(x,  xb,  NX / 4);
  cvt_f32_bf16<<<dim3(NW / 4 / 256), 256, 0, stream>>>(Wq, wqb, NW / 4);
  cvt_f32_bf16<<<dim3(NW / 4 / 256), 256, 0, stream>>>(Wk, wkb, NW / 4);
  cvt_f32_bf16<<<dim3(NW / 4 / 256), 256, 0, stream>>>(Wv, wvb, NW / 4);
  cvt_f32_bf16<<<dim3(NW / 4 / 256), 256, 0, stream>>>(Wo, wob, NW / 4);

  const int M = B_ * T_;  // 4096
  dim3 gg(M / BM, C_ / BN), bb(256);
  gemm_bt<<<gg, bb, 0, stream>>>(xb, wqb, bq, q, nullptr, M, C_, C_, 1);
  gemm_bt<<<gg, bb, 0, stream>>>(xb, wkb, bk, k, nullptr, M, C_, C_, 1);
  gemm_bt<<<gg, bb, 0, stream>>>(xb, wvb, bv, v, nullptr, M, C_, C_, 1);
  attn<<<dim3(B_ * H_ * T_ / 4), bb, 0, stream>>>(q, k, v, ctx);
  gemm_bt<<<gg, bb, 0, stream>>>(ctx, wob, bo, nullptr, out, M, C_, C_, 0);
}

// Round 4
// 286.657 us; speedup vs baseline: 6.1661x; 6.1661x over previous
//
#include <hip/hip_runtime.h>
#include <hip/hip_bf16.h>

#define B_ 2
#define T_ 2048
#define C_ 1024
#define H_ 16
#define D_ 64

typedef unsigned short u16;
typedef __bf16 bf16x8 __attribute__((ext_vector_type(8)));
typedef float floatx4 __attribute__((ext_vector_type(4)));

__device__ __forceinline__ float bf2f(u16 u) {
  union { unsigned int i; float f; } x; x.i = ((unsigned int)u) << 16; return x.f;
}
__device__ __forceinline__ u16 f2bf(float f) {
  union { float f; unsigned int i; } x; x.f = f;
  unsigned int r = x.i + 0x7fffu + ((x.i >> 16) & 1u);  // RNE
  return (u16)(r >> 16);
}

// ---------------------------------------------------------------------------
// fp32 -> bf16 convert (inputs arrive fp32; compute pipeline is bf16 MFMA)
// ---------------------------------------------------------------------------
__global__ __launch_bounds__(256) void cvt_f32_bf16(
    const float* __restrict__ src, u16* __restrict__ dst, int n4)
{
  const int i = (blockIdx.x * 256 + threadIdx.x);
  if (i < n4) {
    float4 f = ((const float4*)src)[i];
    ushort4 o;
    o.x = f2bf(f.x); o.y = f2bf(f.y); o.z = f2bf(f.z); o.w = f2bf(f.w);
    ((ushort4*)dst)[i] = o;
  }
}

// ---------------------------------------------------------------------------
// GEMM: Y[M,N] = X[M,K] @ W[N,K]^T + bias[N]  (bf16 in, fp32 accum)
// mode=1: bf16 out remapped to [B,H,T,D]; mode=0: fp32 out [M,N]
// ---------------------------------------------------------------------------
#define BM 64
#define BN 64
#define BK 32
#define LDK (BK + 8)

__global__ __launch_bounds__(256) void gemm_bt(
    const u16* __restrict__ X, const u16* __restrict__ W,
    const float* __restrict__ bias, u16* __restrict__ Yb,
    float* __restrict__ Yf, int M, int N, int K, int mode)
{
  __shared__ __align__(16) u16 As[BM][LDK];
  __shared__ __align__(16) u16 Bs[BN][LDK];

  const int tid  = threadIdx.x;
  const int wave = tid >> 6;
  const int lane = tid & 63;
  const int m0 = blockIdx.x * BM;
  const int n0 = blockIdx.y * BN;

  const int lrow = tid >> 2;
  const int lcol = (tid & 3) * 8;

  floatx4 acc[4] = {};

  for (int k0 = 0; k0 < K; k0 += BK) {
    *(uint4*)&As[lrow][lcol] =
        *(const uint4*)&X[(size_t)(m0 + lrow) * K + k0 + lcol];
    *(uint4*)&Bs[lrow][lcol] =
        *(const uint4*)&W[(size_t)(n0 + lrow) * K + k0 + lcol];
    __syncthreads();

    const int mrow = wave * 16 + (lane & 15);
    const int kof  = (lane >> 4) * 8;
    bf16x8 a = *(const bf16x8*)&As[mrow][kof];
#pragma unroll
    for (int j = 0; j < 4; ++j) {
      bf16x8 b = *(const bf16x8*)&Bs[j * 16 + (lane & 15)][kof];
      acc[j] = __builtin_amdgcn_mfma_f32_16x16x32_bf16(a, b, acc[j], 0, 0, 0);
    }
    __syncthreads();
  }

  const int rbase = wave * 16 + (lane >> 4) * 4;
#pragma unroll
  for (int j = 0; j < 4; ++j) {
    const int n = n0 + j * 16 + (lane & 15);
    const float bv = bias[n];
#pragma unroll
    for (int r = 0; r < 4; ++r) {
      const int m = m0 + rbase + r;
      const float v = acc[j][r] + bv;
      if (mode) {
        const int b = m >> 11, t = m & (T_ - 1);
        const int h = n >> 6, d = n & (D_ - 1);
        Yb[(((size_t)b * H_ + h) * T_ + t) * D_ + d] = f2bf(v);
      } else {
        Yf[(size_t)m * N + n] = v;
      }
    }
  }
}

// ---------------------------------------------------------------------------
// MFMA flash attention. Q,K,V: [B*H, T, D] bf16. O (ctx): [B, T, C] bf16.
// 1 block = one (bh, 64-row Q-tile); 4 waves x 16 rows. Causal, online softmax.
// ---------------------------------------------------------------------------
#define LDV 72  // padded u16 stride: 144 B, multiple of 16 B -> b128 ok, 2-way banks (free)

__global__ __launch_bounds__(256) void attn_flash(
    const u16* __restrict__ Q, const u16* __restrict__ K,
    const u16* __restrict__ V, u16* __restrict__ O)
{
  __shared__ __align__(16) u16 Ks[64][LDV];      // K-tile, row-major [k][d]
  __shared__ __align__(16) u16 Vt[64][LDV];      // V-tile transposed [d][k]
  __shared__ __align__(16) u16 Ps[4][16][LDV];   // per-wave P round-trip

  const int tid  = threadIdx.x;
  const int wv   = tid >> 6;
  const int lane = tid & 63;
  const int mcol = lane & 15;
  const int quad = lane >> 4;

  const int bx = blockIdx.x;
  const int bh = bx & 31;   // B*H = 32; swizzle: co-resident blocks get mixed iq
  const int iq = bx >> 5;   // Q-tile 0..31

  const size_t base = (size_t)bh * T_ * D_;

  // Q fragments (A-layout: m = lane&15, k = quad*8 + j), two K=32 halves
  const u16* qg = Q + base + (size_t)(iq * 64 + wv * 16 + mcol) * D_ + quad * 8;
  const bf16x8 qf0 = *(const bf16x8*)qg;
  const bf16x8 qf1 = *(const bf16x8*)(qg + 32);

  floatx4 oacc[4] = {};
  float mrow[4] = {-1e30f, -1e30f, -1e30f, -1e30f};
  float lrow[4] = {0.f, 0.f, 0.f, 0.f};

  const int krow = tid >> 2, kcol = (tid & 3) * 16;  // K staging
  const int vk = tid & 63, vd = (tid >> 6) * 16;     // V staging (transpose)

  for (int j = 0; j <= iq; ++j) {
    __syncthreads();
    // --- stage K-tile (as-is) ---
    const u16* kg = K + base + (size_t)(j * 64 + krow) * D_ + kcol;
    *(uint4*)&Ks[krow][kcol]     = *(const uint4*)kg;
    *(uint4*)&Ks[krow][kcol + 8] = *(const uint4*)(kg + 8);
    // --- stage V-tile transposed: Vt[d][k] ---
    const u16* vg = V + base + (size_t)(j * 64 + vk) * D_ + vd;
    union { uint4 u[2]; u16 s[16]; } uv;
    uv.u[0] = *(const uint4*)vg;
    uv.u[1] = *(const uint4*)(vg + 8);
#pragma unroll
    for (int e = 0; e < 16; ++e) Vt[vd + e][vk] = uv.s[e];
    __syncthreads();

    // --- S = (Q/8) . K^T  (compute raw, scale after) ---
    floatx4 sacc[4] = {};
#pragma unroll
    for (int nt = 0; nt < 4; ++nt) {
      bf16x8 b0 = *(const bf16x8*)&Ks[nt * 16 + mcol][quad * 8];
      bf16x8 b1 = *(const bf16x8*)&Ks[nt * 16 + mcol][quad * 8 + 32];
      sacc[nt] = __builtin_amdgcn_mfma_f32_16x16x32_bf16(qf0, b0, sacc[nt], 0, 0, 0);
      sacc[nt] = __builtin_amdgcn_mfma_f32_16x16x32_bf16(qf1, b1, sacc[nt], 0, 0, 0);
    }

    // --- scale + causal mask (diagonal tile only) ---
    float s[4][4];
    const bool diag = (j == iq);
#pragma unroll
    for (int nt = 0; nt < 4; ++nt) {
      const int col = nt * 16 + mcol;
#pragma unroll
      for (int r = 0; r < 4; ++r) {
        float x = sacc[nt][r] * 0.125f;
        if (diag && col > wv * 16 + quad * 4 + r) x = -1e30f;
        s[nt][r] = x;
      }
    }

    // --- online softmax: row max over 64 cols (4 nt-tiles x 16 lanes) ---
    float mx[4];
#pragma unroll
    for (int r = 0; r < 4; ++r)
      mx[r] = fmaxf(fmaxf(s[0][r], s[1][r]), fmaxf(s[2][r], s[3][r]));
#pragma unroll
    for (int off = 1; off < 16; off <<= 1)
#pragma unroll
      for (int r = 0; r < 4; ++r)
        mx[r] = fmaxf(mx[r], __shfl_xor(mx[r], off));

    float alpha[4], psum[4];
#pragma unroll
    for (int r = 0; r < 4; ++r) {
      const float mn = fmaxf(mrow[r], mx[r]);
      alpha[r] = __expf(mrow[r] - mn);
      mrow[r] = mn;
      psum[r] = 0.f;
    }

    // P = exp(s - m): C-layout -> wave-private LDS (bf16) for A-layout reread
#pragma unroll
    for (int nt = 0; nt < 4; ++nt)
#pragma unroll
      for (int r = 0; r < 4; ++r) {
        const float p = __expf(s[nt][r] - mrow[r]);
        psum[r] += p;
        Ps[wv][quad * 4 + r][nt * 16 + mcol] = f2bf(p);
      }
#pragma unroll
    for (int off = 1; off < 16; off <<= 1)
#pragma unroll
      for (int r = 0; r < 4; ++r)
        psum[r] += __shfl_xor(psum[r], off);
#pragma unroll
    for (int r = 0; r < 4; ++r) lrow[r] = lrow[r] * alpha[r] + psum[r];

    // rescale O accumulators (row mapping identical to S's C-layout)
#pragma unroll
    for (int dt = 0; dt < 4; ++dt)
#pragma unroll
      for (int r = 0; r < 4; ++r) oacc[dt][r] *= alpha[r];

    // pin compiler ordering: ds_writes above must precede ds_reads below
    __builtin_amdgcn_wave_barrier();

    // --- O += P . V  (A from Ps, B from Vt) ---
    bf16x8 pa0 = *(const bf16x8*)&Ps[wv][mcol][quad * 8];
    bf16x8 pa1 = *(const bf16x8*)&Ps[wv][mcol][quad * 8 + 32];
#pragma unroll
    for (int dt = 0; dt < 4; ++dt) {
      bf16x8 vb0 = *(const bf16x8*)&Vt[dt * 16 + mcol][quad * 8];
      bf16x8 vb1 = *(const bf16x8*)&Vt[dt * 16 + mcol][quad * 8 + 32];
      oacc[dt] = __builtin_amdgcn_mfma_f32_16x16x32_bf16(pa0, vb0, oacc[dt], 0, 0, 0);
      oacc[dt] = __builtin_amdgcn_mfma_f32_16x16x32_bf16(pa1, vb1, oacc[dt], 0, 0, 0);
    }
  }

  // --- epilogue: O / l -> ctx [B,T,C] bf16 ---
  const int b = bh >> 4, h = bh & (H_ - 1);
  float invl[4];
#pragma unroll
  for (int r = 0; r < 4; ++r) invl[r] = 1.f / lrow[r];
#pragma unroll
  for (int dt = 0; dt < 4; ++dt) {
    const int c = h * D_ + dt * 16 + mcol;
#pragma unroll
    for (int r = 0; r < 4; ++r) {
      const int t = iq * 64 + wv * 16 + quad * 4 + r;
      O[((size_t)b * T_ + t) * C_ + c] = f2bf(oacc[dt][r] * invl[r]);
    }
  }
}

// ---------------------------------------------------------------------------
extern "C" void kernel_launch(void* const* d_in, const int* in_sizes, int n_in,
                              void* d_out, int out_size, void* d_ws, size_t ws_size,
                              hipStream_t stream) {
  const float* x  = (const float*)d_in[0];
  const float* Wq = (const float*)d_in[1];
  const float* bq = (const float*)d_in[2];
  const float* Wk = (const float*)d_in[3];
  const float* bk = (const float*)d_in[4];
  const float* Wv = (const float*)d_in[5];
  const float* bv = (const float*)d_in[6];
  const float* Wo = (const float*)d_in[7];
  const float* bo = (const float*)d_in[8];
  float* out = (float*)d_out;

  const size_t NX = (size_t)B_ * T_ * C_;  // 4M
  const size_t NW = (size_t)C_ * C_;       // 1M

  u16* xb  = (u16*)d_ws;
  u16* wqb = xb  + NX;
  u16* wkb = wqb + NW;
  u16* wvb = wkb + NW;
  u16* wob = wvb + NW;
  u16* q   = wob + NW;
  u16* k   = q   + NX;
  u16* v   = k   + NX;
  u16* ctx = v   + NX;

  cvt_f32_bf16<<<dim3(NX / 4 / 256), 256, 0, stream>>>(x,  xb,  NX / 4);
  cvt_f32_bf16<<<dim3(NW / 4 / 256), 256, 0, stream>>>(Wq, wqb, NW / 4);
  cvt_f32_bf16<<<dim3(NW / 4 / 256), 256, 0, stream>>>(Wk, wkb, NW / 4);
  cvt_f32_bf16<<<dim3(NW / 4 / 256), 256, 0, stream>>>(Wv, wvb, NW / 4);
  cvt_f32_bf16<<<dim3(NW / 4 / 256), 256, 0, stream>>>(Wo, wob, NW / 4);

  const int M = B_ * T_;  // 4096
  dim3 gg(M / BM, C_ / BN), bb(256);
  gemm_bt<<<gg, bb, 0, stream>>>(xb, wqb, bq, q, nullptr, M, C_, C_, 1);
  gemm_bt<<<gg, bb, 0, stream>>>(xb, wkb, bk, k, nullptr, M, C_, C_, 1);
  gemm_bt<<<gg, bb, 0, stream>>>(xb, wvb, bv, v, nullptr, M, C_, C_, 1);
  attn_flash<<<dim3(B_ * H_ * (T_ / 64)), bb, 0, stream>>>(q, k, v, ctx);
  gemm_bt<<<gg, bb, 0, stream>>>(ctx, wob, bo, nullptr, out, M, C_, C_, 0);
}

// Round 5
// 249.236 us; speedup vs baseline: 7.0918x; 1.1501x over previous
//
#include <hip/hip_runtime.h>
#include <hip/hip_bf16.h>

#define B_ 2
#define T_ 2048
#define C_ 1024
#define H_ 16
#define D_ 64

typedef unsigned short u16;
typedef __bf16 bf16x8 __attribute__((ext_vector_type(8)));
typedef float floatx4 __attribute__((ext_vector_type(4)));

__device__ __forceinline__ float bf2f(u16 u) {
  union { unsigned int i; float f; } x; x.i = ((unsigned int)u) << 16; return x.f;
}
__device__ __forceinline__ u16 f2bf(float f) {
  union { float f; unsigned int i; } x; x.f = f;
  unsigned int r = x.i + 0x7fffu + ((x.i >> 16) & 1u);  // RNE
  return (u16)(r >> 16);
}

// async 16B global -> LDS (m97-verified path; emits global_load_lds_dwordx4)
__device__ __forceinline__ void gld16(void* lds, const void* g) {
  __builtin_amdgcn_global_load_lds(
      (const __attribute__((address_space(1))) unsigned int*)g,
      (__attribute__((address_space(3))) unsigned int*)lds, 16, 0, 0);
}

// ---------------------------------------------------------------------------
// fp32 -> bf16 convert
// ---------------------------------------------------------------------------
__global__ __launch_bounds__(256) void cvt_f32_bf16(
    const float* __restrict__ src, u16* __restrict__ dst, int n4)
{
  const int i = (blockIdx.x * 256 + threadIdx.x);
  if (i < n4) {
    float4 f = ((const float4*)src)[i];
    ushort4 o;
    o.x = f2bf(f.x); o.y = f2bf(f.y); o.z = f2bf(f.z); o.w = f2bf(f.w);
    ((ushort4*)dst)[i] = o;
  }
}

// ---------------------------------------------------------------------------
// GEMM (m97 structure): Y[M,N] = X[M,K] @ W[N,K]^T + bias, 64x128 tile, BK=32.
// M=4096, N=K=1024 fixed. Staging via global_load_lds (contiguous lane order,
// LDS unpadded). 4 waves in 2x2; each wave: 2x4 16x16 frags, 8 MFMA/K-step.
// mode: 0 = fp32 out [M,N]
//       1 = bf16 out remapped [B,H,T,D]
//       2 = bf16 out remapped [B,H,T,D], scaled by 0.125 (Q: fold 1/sqrt(D))
//       3 = bf16 out remapped [B,H,D,T] (V transposed for flash PV)
// ---------------------------------------------------------------------------
#define BM 64
#define BN 128
#define BK 32

__global__ __launch_bounds__(256) void gemm_bt(
    const u16* __restrict__ X, const u16* __restrict__ W,
    const float* __restrict__ bias, u16* __restrict__ Yb,
    float* __restrict__ Yf, int mode)
{
  const int K = C_, N = C_;
  __shared__ __align__(16) u16 As[BM * BK];   // 4 KB row-major [64][32]
  __shared__ __align__(16) u16 Bs[BN * BK];   // 8 KB row-major [128][32]

  const int tid  = threadIdx.x;
  const int wv   = tid >> 6;
  const int lane = tid & 63;
  const int mcol = lane & 15;
  const int quad = lane >> 4;
  const int wr = wv >> 1, wc = wv & 1;
  const int m0 = blockIdx.x * BM;
  const int n0 = blockIdx.y * BN;

  const int srow = tid >> 2;            // 0..63
  const int scol = (tid & 3) * 8;       // 0,8,16,24

  floatx4 acc[2][4] = {};

  const u16* xp = X + (size_t)(m0 + srow) * K + scol;
  const u16* wp0 = W + (size_t)(n0 + srow) * K + scol;
  const u16* wp1 = W + (size_t)(n0 + 64 + srow) * K + scol;

  for (int k0 = 0; k0 < K; k0 += BK) {
    gld16(&As[(size_t)tid * 8], xp + k0);
    gld16(&Bs[(size_t)tid * 8], wp0 + k0);
    gld16(&Bs[(size_t)(256 + tid) * 8], wp1 + k0);
    __syncthreads();   // drains vmcnt(0): staged data visible

    bf16x8 a[2], b[4];
#pragma unroll
    for (int rf = 0; rf < 2; ++rf)
      a[rf] = *(const bf16x8*)&As[(wr * 32 + rf * 16 + mcol) * BK + quad * 8];
#pragma unroll
    for (int cf = 0; cf < 4; ++cf)
      b[cf] = *(const bf16x8*)&Bs[(wc * 64 + cf * 16 + mcol) * BK + quad * 8];
#pragma unroll
    for (int rf = 0; rf < 2; ++rf)
#pragma unroll
      for (int cf = 0; cf < 4; ++cf)
        acc[rf][cf] = __builtin_amdgcn_mfma_f32_16x16x32_bf16(
            a[rf], b[cf], acc[rf][cf], 0, 0, 0);
    __syncthreads();   // protect LDS from next iteration's staging
  }

  // Epilogue. C/D: col = mcol, row = quad*4 + reg
#pragma unroll
  for (int cf = 0; cf < 4; ++cf) {
    const int n = n0 + wc * 64 + cf * 16 + mcol;
    const float bv = bias[n];
#pragma unroll
    for (int rf = 0; rf < 2; ++rf) {
#pragma unroll
      for (int r = 0; r < 4; ++r) {
        const int m = m0 + wr * 32 + rf * 16 + quad * 4 + r;
        float v = acc[rf][cf][r] + bv;
        if (mode == 0) {
          Yf[(size_t)m * N + n] = v;
        } else {
          const int bb = m >> 11, t = m & (T_ - 1);
          const int h = n >> 6, d = n & (D_ - 1);
          if (mode == 2) v *= 0.125f;
          size_t idx;
          if (mode == 3) idx = (((size_t)bb * H_ + h) * D_ + d) * T_ + t;
          else           idx = (((size_t)bb * H_ + h) * T_ + t) * D_ + d;
          Yb[idx] = f2bf(v);
        }
      }
    }
  }
}

// ---------------------------------------------------------------------------
// MFMA flash attention, causal, online softmax.
// Q: [B*H, T, D] bf16 PRE-SCALED by 1/8. K: [B*H, T, D] bf16.
// Vt: [B*H, D, T] bf16 (pre-transposed by projection). O: [B, T, C] bf16.
// Block = (bh, tile-pair pp): processes Q-tiles pp and 31-pp -> uniform
// 33 K-iterations per block. 512 blocks x 256 threads.
// l (softmax denom) via MFMA: Vt LDS row 64 = ones -> oacc[4] col0 = rowsum.
// P-store XOR-swizzle (granule ^ quad): 0 LDS store conflicts.
// ---------------------------------------------------------------------------
#define LDV 72  // u16 row stride (144 B)

__global__ __launch_bounds__(256) void attn_flash(
    const u16* __restrict__ Q, const u16* __restrict__ K,
    const u16* __restrict__ Vg, u16* __restrict__ O)
{
  __shared__ __align__(16) u16 Ks[64][LDV];   // K-tile [k][d]
  __shared__ __align__(16) u16 Vt[80][LDV];   // V-tile [d][k]; rows 64..79: ones/zeros
  __shared__ __align__(16) u16 Ps[4][16][LDV];// per-wave P (swizzled)

  const int tid  = threadIdx.x;
  const int wv   = tid >> 6;
  const int lane = tid & 63;
  const int mcol = lane & 15;
  const int quad = lane >> 4;

  const int bh = blockIdx.x & 31;
  const int pp = blockIdx.x >> 5;           // 0..15

  const size_t base = (size_t)bh * T_ * D_;
  const int b = bh >> 4, h = bh & (H_ - 1);

  // ones-row block for MFMA row-sum (rows 64..79 of Vt), written once
  for (int idx = tid; idx < 16 * LDV; idx += 256) {
    const int row = idx / LDV, col = idx - row * LDV;
    Vt[64 + row][col] = (row == 0 && col < 64) ? (u16)0x3F80 : (u16)0;
  }

  const int srow = tid >> 2;            // staging row 0..63
  const int scol = (tid & 3) * 16;      // staging col {0,16,32,48}

  // P-store swizzle constants (store: row m, granule g -> g ^ (m>>2))
  const int h3 = mcol >> 3, lo = mcol & 7;
  u16* psw = &Ps[wv][0][0];
  int colsw[4];
#pragma unroll
  for (int nt = 0; nt < 4; ++nt)
    colsw[nt] = (((nt * 2 + h3) ^ quad) * 8) + lo;
  const int g0 = quad ^ (mcol >> 2);    // read-side swizzled granule

  for (int half = 0; half < 2; ++half) {
    const int iq = half ? (31 - pp) : pp;

    const u16* qg = Q + base + (size_t)(iq * 64 + wv * 16 + mcol) * D_ + quad * 8;
    const bf16x8 qf0 = *(const bf16x8*)qg;
    const bf16x8 qf1 = *(const bf16x8*)(qg + 32);

    floatx4 oacc[5] = {};   // [0..3]: D-cols; [4]: rowsum (col 0)
    float mrow[4] = {-1e30f, -1e30f, -1e30f, -1e30f};

    for (int j = 0; j <= iq; ++j) {
      __syncthreads();  // prior compute done before we overwrite tiles
      const u16* kg = K + base + (size_t)(j * 64 + srow) * D_ + scol;
      *(uint4*)&Ks[srow][scol]     = *(const uint4*)kg;
      *(uint4*)&Ks[srow][scol + 8] = *(const uint4*)(kg + 8);
      const u16* vg = Vg + (size_t)bh * D_ * T_ + (size_t)srow * T_ + j * 64 + scol;
      *(uint4*)&Vt[srow][scol]     = *(const uint4*)vg;
      *(uint4*)&Vt[srow][scol + 8] = *(const uint4*)(vg + 8);
      __syncthreads();

      // --- S = Qs . K^T (Q pre-scaled) ---
      floatx4 sacc[4] = {};
#pragma unroll
      for (int nt = 0; nt < 4; ++nt) {
        bf16x8 b0 = *(const bf16x8*)&Ks[nt * 16 + mcol][quad * 8];
        bf16x8 b1 = *(const bf16x8*)&Ks[nt * 16 + mcol][quad * 8 + 32];
        sacc[nt] = __builtin_amdgcn_mfma_f32_16x16x32_bf16(qf0, b0, sacc[nt], 0, 0, 0);
        sacc[nt] = __builtin_amdgcn_mfma_f32_16x16x32_bf16(qf1, b1, sacc[nt], 0, 0, 0);
      }

      // --- causal mask (diagonal tile only) ---
      if (j == iq) {
#pragma unroll
        for (int nt = 0; nt < 4; ++nt) {
          const int col = nt * 16 + mcol;
#pragma unroll
          for (int r = 0; r < 4; ++r)
            if (col > wv * 16 + quad * 4 + r) sacc[nt][r] = -1e30f;
        }
      }

      // --- row max over 64 cols ---
      float mx[4];
#pragma unroll
      for (int r = 0; r < 4; ++r)
        mx[r] = fmaxf(fmaxf(sacc[0][r], sacc[1][r]), fmaxf(sacc[2][r], sacc[3][r]));
#pragma unroll
      for (int off = 1; off < 16; off <<= 1)
#pragma unroll
        for (int r = 0; r < 4; ++r)
          mx[r] = fmaxf(mx[r], __shfl_xor(mx[r], off));

      float alpha[4];
#pragma unroll
      for (int r = 0; r < 4; ++r) {
        const float mn = fmaxf(mrow[r], mx[r]);
        alpha[r] = __expf(mrow[r] - mn);
        mrow[r] = mn;
      }

      // --- P = exp(s - m) -> swizzled LDS (bf16) ---
#pragma unroll
      for (int nt = 0; nt < 4; ++nt)
#pragma unroll
        for (int r = 0; r < 4; ++r) {
          const float p = __expf(sacc[nt][r] - mrow[r]);
          psw[(quad * 4 + r) * LDV + colsw[nt]] = f2bf(p);
        }

      // rescale accumulators (incl. rowsum)
#pragma unroll
      for (int dt = 0; dt < 5; ++dt)
#pragma unroll
        for (int r = 0; r < 4; ++r) oacc[dt][r] *= alpha[r];

      __builtin_amdgcn_wave_barrier();  // order Ps writes before reads

      // --- O += P . V ; dt=4 accumulates row-sums via ones-row ---
      bf16x8 pa0 = *(const bf16x8*)&psw[mcol * LDV + g0 * 8];
      bf16x8 pa1 = *(const bf16x8*)&psw[mcol * LDV + (g0 + 4) * 8];
#pragma unroll
      for (int dt = 0; dt < 5; ++dt) {
        bf16x8 vb0 = *(const bf16x8*)&Vt[dt * 16 + mcol][quad * 8];
        bf16x8 vb1 = *(const bf16x8*)&Vt[dt * 16 + mcol][quad * 8 + 32];
        oacc[dt] = __builtin_amdgcn_mfma_f32_16x16x32_bf16(pa0, vb0, oacc[dt], 0, 0, 0);
        oacc[dt] = __builtin_amdgcn_mfma_f32_16x16x32_bf16(pa1, vb1, oacc[dt], 0, 0, 0);
      }
    }

    // --- epilogue: fetch l from col 0 of oacc[4] (lane quad*16), divide ---
    float invl[4];
#pragma unroll
    for (int r = 0; r < 4; ++r)
      invl[r] = 1.f / __shfl(oacc[4][r], lane & 48);
#pragma unroll
    for (int dt = 0; dt < 4; ++dt) {
      const int c = h * D_ + dt * 16 + mcol;
#pragma unroll
      for (int r = 0; r < 4; ++r) {
        const int t = iq * 64 + wv * 16 + quad * 4 + r;
        O[((size_t)b * T_ + t) * C_ + c] = f2bf(oacc[dt][r] * invl[r]);
      }
    }
  }
}

// ---------------------------------------------------------------------------
extern "C" void kernel_launch(void* const* d_in, const int* in_sizes, int n_in,
                              void* d_out, int out_size, void* d_ws, size_t ws_size,
                              hipStream_t stream) {
  const float* x  = (const float*)d_in[0];
  const float* Wq = (const float*)d_in[1];
  const float* bq = (const float*)d_in[2];
  const float* Wk = (const float*)d_in[3];
  const float* bk = (const float*)d_in[4];
  const float* Wv = (const float*)d_in[5];
  const float* bv = (const float*)d_in[6];
  const float* Wo = (const float*)d_in[7];
  const float* bo = (const float*)d_in[8];
  float* out = (float*)d_out;

  const size_t NX = (size_t)B_ * T_ * C_;  // 4M
  const size_t NW = (size_t)C_ * C_;       // 1M

  u16* xb  = (u16*)d_ws;
  u16* wqb = xb  + NX;
  u16* wkb = wqb + NW;
  u16* wvb = wkb + NW;
  u16* wob = wvb + NW;
  u16* q   = wob + NW;
  u16* k   = q   + NX;
  u16* v   = k   + NX;   // [B,H,D,T] layout
  u16* ctx = v   + NX;

  cvt_f32_bf16<<<dim3(NX / 4 / 256), 256, 0, stream>>>(x,  xb,  NX / 4);
  cvt_f32_bf16<<<dim3(NW / 4 / 256), 256, 0, stream>>>(Wq, wqb, NW / 4);
  cvt_f32_bf16<<<dim3(NW / 4 / 256), 256, 0, stream>>>(Wk, wkb, NW / 4);
  cvt_f32_bf16<<<dim3(NW / 4 / 256), 256, 0, stream>>>(Wv, wvb, NW / 4);
  cvt_f32_bf16<<<dim3(NW / 4 / 256), 256, 0, stream>>>(Wo, wob, NW / 4);

  const int M = B_ * T_;  // 4096
  dim3 gg(M / BM, C_ / BN), bb(256);
  gemm_bt<<<gg, bb, 0, stream>>>(xb, wqb, bq, q, nullptr, 2);  // Q, pre-scaled
  gemm_bt<<<gg, bb, 0, stream>>>(xb, wkb, bk, k, nullptr, 1);  // K
  gemm_bt<<<gg, bb, 0, stream>>>(xb, wvb, bv, v, nullptr, 3);  // V, transposed
  attn_flash<<<dim3(512), bb, 0, stream>>>(q, k, v, ctx);
  gemm_bt<<<gg, bb, 0, stream>>>(ctx, wob, bo, nullptr, out, 0);
}

// Round 6
// 200.576 us; speedup vs baseline: 8.8123x; 1.2426x over previous
//
#include <hip/hip_runtime.h>
#include <hip/hip_bf16.h>

#define B_ 2
#define T_ 2048
#define C_ 1024
#define H_ 16
#define D_ 64

typedef unsigned short u16;
typedef __bf16 bf16x8 __attribute__((ext_vector_type(8)));
typedef float floatx4 __attribute__((ext_vector_type(4)));

__device__ __forceinline__ float bf2f(u16 u) {
  union { unsigned int i; float f; } x; x.i = ((unsigned int)u) << 16; return x.f;
}
__device__ __forceinline__ u16 f2bf(float f) {  // RNE
  union { float f; unsigned int i; } x; x.f = f;
  unsigned int r = x.i + 0x7fffu + ((x.i >> 16) & 1u);
  return (u16)(r >> 16);
}

// async 16B global -> LDS (wave-uniform base + lane*16; round-5-verified)
__device__ __forceinline__ void gld16(void* lds, const void* g) {
  __builtin_amdgcn_global_load_lds(
      (const __attribute__((address_space(1))) unsigned int*)g,
      (__attribute__((address_space(3))) unsigned int*)lds, 16, 0, 0);
}

// ---------------------------------------------------------------------------
// Fused fp32 -> bf16 convert for x + 4 weights (one dispatch).
// ---------------------------------------------------------------------------
#define NXF4 1048576   // (B*T*C)/4
#define NWF4 262144    // (C*C)/4

__global__ __launch_bounds__(256) void cvt_all(
    const float* __restrict__ x,  const float* __restrict__ Wq,
    const float* __restrict__ Wk, const float* __restrict__ Wv,
    const float* __restrict__ Wo, u16* __restrict__ dst_base)
{
  const int i = blockIdx.x * 256 + threadIdx.x;  // float4 index, < 2097152
  const float* src; size_t off;
  if (i < NXF4)               { src = x;  off = i; }
  else if (i < NXF4 + NWF4)   { src = Wq; off = i - NXF4; }
  else if (i < NXF4 + 2*NWF4) { src = Wk; off = i - (NXF4 + NWF4); }
  else if (i < NXF4 + 3*NWF4) { src = Wv; off = i - (NXF4 + 2*NWF4); }
  else                        { src = Wo; off = i - (NXF4 + 3*NWF4); }
  float4 f = ((const float4*)src)[off];
  ushort4 o;
  o.x = f2bf(f.x); o.y = f2bf(f.y); o.z = f2bf(f.z); o.w = f2bf(f.w);
  ((ushort4*)dst_base)[i] = o;   // ws layout: xb | wqb | wkb | wvb | wob
}

// ---------------------------------------------------------------------------
// m97-style GEMM: Y[M,N] = X[M,K] @ W[N,K]^T + bias. 128x128 tile, BK=32.
// M=4096, N=K=1024. Staging via gld16 (lane-linear, unpadded 64 B LDS rows).
// qkv=1: blockIdx.z selects weight z (W contiguous, stride C*C), bias bz,
//        output mode z: 0=Q ([B,H,T,D], scaled 0.125/ln2 -> log2-domain
//        scores), 1=K ([B,H,T,D]), 2=V transposed ([B,H,D,T]).
// qkv=0: fp32 out [M,N] (final projection).
// ---------------------------------------------------------------------------
#define QSCALE 0.1803368801111f  // 0.125 / ln(2)

__global__ __launch_bounds__(256) void gemm128(
    const u16* __restrict__ X, const u16* __restrict__ Wb,
    const float* __restrict__ b0, const float* __restrict__ b1,
    const float* __restrict__ b2,
    u16* __restrict__ Yq, u16* __restrict__ Yk, u16* __restrict__ Yv,
    float* __restrict__ Yf, int qkv)
{
  const int K = C_, N = C_;
  __shared__ __align__(16) u16 As[128 * 32];  // 8 KB
  __shared__ __align__(16) u16 Bs[128 * 32];  // 8 KB

  const int tid  = threadIdx.x;
  const int wv   = tid >> 6;
  const int lane = tid & 63;
  const int mcol = lane & 15;
  const int quad = lane >> 4;
  const int wr = wv >> 1, wc = wv & 1;
  const int m0 = blockIdx.x * 128;
  const int n0 = blockIdx.y * 128;
  const int z  = qkv ? (int)blockIdx.z : 0;

  const u16* W = qkv ? (Wb + (size_t)z * C_ * C_) : Wb;
  const float* bias = qkv ? (z == 0 ? b0 : z == 1 ? b1 : b2) : b0;

  const int srow = tid >> 2;          // 0..63
  const int scol = (tid & 3) * 8;     // granule*8
  const u16* xp0 = X + (size_t)(m0 + srow) * K + scol;
  const u16* xp1 = xp0 + (size_t)64 * K;
  const u16* wp0 = W + (size_t)(n0 + srow) * K + scol;
  const u16* wp1 = wp0 + (size_t)64 * K;

  floatx4 acc[4][4] = {};

  for (int k0 = 0; k0 < K; k0 += 32) {
    gld16(&As[tid * 8],        xp0 + k0);
    gld16(&As[2048 + tid * 8], xp1 + k0);
    gld16(&Bs[tid * 8],        wp0 + k0);
    gld16(&Bs[2048 + tid * 8], wp1 + k0);
    __syncthreads();   // drains vmcnt(0)

    bf16x8 a[4], b[4];
#pragma unroll
    for (int rf = 0; rf < 4; ++rf)
      a[rf] = *(const bf16x8*)&As[(wr * 64 + rf * 16 + mcol) * 32 + quad * 8];
#pragma unroll
    for (int cf = 0; cf < 4; ++cf)
      b[cf] = *(const bf16x8*)&Bs[(wc * 64 + cf * 16 + mcol) * 32 + quad * 8];
#pragma unroll
    for (int rf = 0; rf < 4; ++rf)
#pragma unroll
      for (int cf = 0; cf < 4; ++cf)
        acc[rf][cf] = __builtin_amdgcn_mfma_f32_16x16x32_bf16(
            a[rf], b[cf], acc[rf][cf], 0, 0, 0);
    __syncthreads();
  }

  // Epilogue. C/D: col = mcol, row = quad*4 + reg.
#pragma unroll
  for (int cf = 0; cf < 4; ++cf) {
    const int n = n0 + wc * 64 + cf * 16 + mcol;
    const float bv = bias[n];
#pragma unroll
    for (int rf = 0; rf < 4; ++rf) {
#pragma unroll
      for (int r = 0; r < 4; ++r) {
        const int m = m0 + wr * 64 + rf * 16 + quad * 4 + r;
        const float v = acc[rf][cf][r] + bv;
        if (!qkv) {
          Yf[(size_t)m * N + n] = v;
        } else {
          const int bb = m >> 11, t = m & (T_ - 1);
          const int h = n >> 6, d = n & (D_ - 1);
          if (z == 0)
            Yq[(((size_t)bb * H_ + h) * T_ + t) * D_ + d] = f2bf(v * QSCALE);
          else if (z == 1)
            Yk[(((size_t)bb * H_ + h) * T_ + t) * D_ + d] = f2bf(v);
          else
            Yv[(((size_t)bb * H_ + h) * D_ + d) * T_ + t] = f2bf(v);
        }
      }
    }
  }
}

// ---------------------------------------------------------------------------
// MFMA flash attention, causal, FIXED-BASE softmax (no running max):
// scores are in log2 domain (Q pre-scaled by 0.125/ln2); p = exp2(s) is
// exact-ratio softmax, safe since |s| << 126. l via ones-row MFMA.
// Q,K: [B*H,T,D] bf16. Vt: [B*H,D,T] bf16. O(ctx): [B,T,C] bf16.
// K/V staged by gld16 with granule-XOR-swizzled source (slot = g ^ (row&7))
// so unpadded 128 B LDS rows read conflict-free.
// Block = (bh, pair pp): Q-tiles pp and 31-pp -> uniform 33 K-iters.
// ---------------------------------------------------------------------------
__global__ __launch_bounds__(256) void attn_flash(
    const u16* __restrict__ Q, const u16* __restrict__ K,
    const u16* __restrict__ Vg, u16* __restrict__ O)
{
  __shared__ __align__(16) u16 Ks[64 * 64];     // 8 KB, swizzled granules
  __shared__ __align__(16) u16 Vt[80 * 64];     // 10 KB; rows 64..79 ones/zeros
  __shared__ __align__(16) u16 Ps[4][16 * 72];  // 9 KB, per-wave P

  const int tid  = threadIdx.x;
  const int wv   = tid >> 6;
  const int lane = tid & 63;
  const int mcol = lane & 15;
  const int quad = lane >> 4;

  const int bh = blockIdx.x & 31;
  const int pp = blockIdx.x >> 5;
  const size_t base = (size_t)bh * T_ * D_;
  const int b = bh >> 4, h = bh & (H_ - 1);

  // ones rows (row 64 = all ones -> swizzle-invariant; 65..79 zeros)
  for (int idx = tid; idx < 16 * 64; idx += 256)
    Vt[64 * 64 + idx] = (idx < 64) ? (u16)0x3F80 : (u16)0;

  // staging: chunk c = wv*2+p covers tile rows c*8 + (lane>>3)
  const int srow = lane >> 3;                 // 0..7 (== row&7, since c*8≡0 mod 8)
  const int sg   = (lane & 7) ^ srow;         // swizzled source granule
  const int c0 = wv * 2, c1 = wv * 2 + 1;

  // K/Vt read slot offset: slot = quad ^ (row&7), row&7 = mcol&7
  const int sl0 = (quad ^ (mcol & 7)) * 8;

  // Ps store/read swizzle (round-5-verified)
  const int h3 = mcol >> 3, lo = mcol & 7;
  u16* psw = &Ps[wv][0];
  int colsw[4];
#pragma unroll
  for (int nt = 0; nt < 4; ++nt)
    colsw[nt] = (((nt * 2 + h3) ^ quad) * 8) + lo;
  const int g0 = quad ^ (mcol >> 2);

  for (int half = 0; half < 2; ++half) {
    const int iq = half ? (31 - pp) : pp;

    const u16* qg = Q + base + (size_t)(iq * 64 + wv * 16 + mcol) * D_ + quad * 8;
    const bf16x8 qf0 = *(const bf16x8*)qg;
    const bf16x8 qf1 = *(const bf16x8*)(qg + 32);

    floatx4 oacc[5] = {};   // [0..3] D-cols; [4] rowsum via ones-row

    for (int j = 0; j <= iq; ++j) {
      __syncthreads();   // prior compute done before restage
      gld16(&Ks[c0 * 512 + lane * 8],
            K + base + (size_t)(j * 64 + c0 * 8 + srow) * D_ + sg * 8);
      gld16(&Ks[c1 * 512 + lane * 8],
            K + base + (size_t)(j * 64 + c1 * 8 + srow) * D_ + sg * 8);
      gld16(&Vt[c0 * 512 + lane * 8],
            Vg + (size_t)bh * D_ * T_ + (size_t)(c0 * 8 + srow) * T_ + j * 64 + sg * 8);
      gld16(&Vt[c1 * 512 + lane * 8],
            Vg + (size_t)bh * D_ * T_ + (size_t)(c1 * 8 + srow) * T_ + j * 64 + sg * 8);
      __syncthreads();   // vmcnt(0) drain: staged data visible

      // --- S = Q . K^T (log2 domain) ---
      floatx4 sacc[4] = {};
#pragma unroll
      for (int nt = 0; nt < 4; ++nt) {
        const u16* kr = &Ks[(nt * 16 + mcol) * 64];
        bf16x8 kb0 = *(const bf16x8*)&kr[sl0];
        bf16x8 kb1 = *(const bf16x8*)&kr[sl0 ^ 32];
        sacc[nt] = __builtin_amdgcn_mfma_f32_16x16x32_bf16(qf0, kb0, sacc[nt], 0, 0, 0);
        sacc[nt] = __builtin_amdgcn_mfma_f32_16x16x32_bf16(qf1, kb1, sacc[nt], 0, 0, 0);
      }

      // --- causal mask (diagonal tile) ---
      if (j == iq) {
#pragma unroll
        for (int nt = 0; nt < 4; ++nt) {
          const int col = nt * 16 + mcol;
#pragma unroll
          for (int r = 0; r < 4; ++r)
            if (col > wv * 16 + quad * 4 + r) sacc[nt][r] = -1e30f;
        }
      }

      // --- P = exp2(s) -> swizzled LDS (bf16, +0x8000 round) ---
#pragma unroll
      for (int nt = 0; nt < 4; ++nt)
#pragma unroll
        for (int r = 0; r < 4; ++r) {
          const float p = exp2f(sacc[nt][r]);
          psw[(quad * 4 + r) * 72 + colsw[nt]] =
              (u16)((__float_as_uint(p) + 0x8000u) >> 16);
        }

      __builtin_amdgcn_wave_barrier();  // order Ps writes before reads

      // --- O += P . V ; dt=4 = rowsum (ones-row) ---
      bf16x8 pa0 = *(const bf16x8*)&psw[mcol * 72 + g0 * 8];
      bf16x8 pa1 = *(const bf16x8*)&psw[mcol * 72 + g0 * 8 + 32];
#pragma unroll
      for (int dt = 0; dt < 5; ++dt) {
        const u16* vr = &Vt[(dt * 16 + mcol) * 64];
        bf16x8 vb0 = *(const bf16x8*)&vr[sl0];
        bf16x8 vb1 = *(const bf16x8*)&vr[sl0 ^ 32];
        oacc[dt] = __builtin_amdgcn_mfma_f32_16x16x32_bf16(pa0, vb0, oacc[dt], 0, 0, 0);
        oacc[dt] = __builtin_amdgcn_mfma_f32_16x16x32_bf16(pa1, vb1, oacc[dt], 0, 0, 0);
      }
    }

    // --- epilogue: l sits in col 0 of oacc[4] (lanes mcol==0) ---
    float invl[4];
#pragma unroll
    for (int r = 0; r < 4; ++r)
      invl[r] = 1.f / __shfl(oacc[4][r], lane & 48);
#pragma unroll
    for (int dt = 0; dt < 4; ++dt) {
      const int c = h * D_ + dt * 16 + mcol;
#pragma unroll
      for (int r = 0; r < 4; ++r) {
        const int t = iq * 64 + wv * 16 + quad * 4 + r;
        O[((size_t)b * T_ + t) * C_ + c] = f2bf(oacc[dt][r] * invl[r]);
      }
    }
  }
}

// ---------------------------------------------------------------------------
extern "C" void kernel_launch(void* const* d_in, const int* in_sizes, int n_in,
                              void* d_out, int out_size, void* d_ws, size_t ws_size,
                              hipStream_t stream) {
  const float* x  = (const float*)d_in[0];
  const float* Wq = (const float*)d_in[1];
  const float* bq = (const float*)d_in[2];
  const float* Wk = (const float*)d_in[3];
  const float* bk = (const float*)d_in[4];
  const float* Wv = (const float*)d_in[5];
  const float* bv = (const float*)d_in[6];
  const float* Wo = (const float*)d_in[7];
  const float* bo = (const float*)d_in[8];
  float* out = (float*)d_out;

  const size_t NX = (size_t)B_ * T_ * C_;  // 4M
  const size_t NW = (size_t)C_ * C_;       // 1M

  u16* xb  = (u16*)d_ws;      // bf16 x
  u16* wqb = xb  + NX;        // bf16 weights, CONTIGUOUS (qkv GEMM indexes by z)
  u16* wkb = wqb + NW;
  u16* wvb = wkb + NW;
  u16* wob = wvb + NW;
  u16* q   = wob + NW;        // [B,H,T,D]
  u16* k   = q   + NX;        // [B,H,T,D]
  u16* v   = k   + NX;        // [B,H,D,T]
  u16* ctx = v   + NX;        // [B,T,C]

  cvt_all<<<dim3((NXF4 + 4 * NWF4) / 256), 256, 0, stream>>>(x, Wq, Wk, Wv, Wo, xb);

  gemm128<<<dim3(32, 8, 3), 256, 0, stream>>>(
      xb, wqb, bq, bk, bv, q, k, v, nullptr, 1);

  attn_flash<<<dim3(512), 256, 0, stream>>>(q, k, v, ctx);

  gemm128<<<dim3(32, 8, 1), 256, 0, stream>>>(
      ctx, wob, bo, nullptr, nullptr, nullptr, nullptr, nullptr, out, 0);
}